// Round 6
// baseline (268.792 us; speedup 1.0000x reference)
//
#include <hip/hip_runtime.h>
#include <hip/hip_bf16.h>
#include <hip/hip_fp16.h>

#define HW      262144   // 512*512 spatial positions
#define NCH     128      // channels (GEMM K)
#define NCLS    128      // classes  (GEMM N)
#define KROWS   131072   // gathered rows
#define NBKT    16384    // HW/16: one bucket per 16-position group (= per wave)
#define CAP     48       // entries per bucket (Poisson mean 8; P(>48) ~ 1e-25)

typedef short  bf16x8 __attribute__((ext_vector_type(8)));
typedef float  f32x4  __attribute__((ext_vector_type(4)));

__device__ inline ushort f2bf(float f) {
    union { float f; unsigned u; } v; v.f = f;
    unsigned u = v.u;
    unsigned r = (u + 0x7FFFu + ((u >> 16) & 1u)) >> 16;   // RNE
    return (ushort)r;
}

// blocks 0..63: W fp32 -> bf16 in MFMA B-fragment order
//   Wf[((nt*4+kk)*64 + lane)*8 + j] = bf16( W[nt*16+(lane&15)][kk*32+(lane>>4)*8+j] )
// blocks 64..79: zero the 16384-int bucket-count array
__global__ __launch_bounds__(256) void prep(const float* __restrict__ Wc,
                                            ushort* __restrict__ Wf,
                                            int4* __restrict__ cnt4) {
    if (blockIdx.x < 64) {
        int e    = blockIdx.x * 256 + threadIdx.x;   // 0..16383
        int j    = e & 7;
        int slot = e >> 3;
        int lane = slot & 63;
        int kk   = (slot >> 6) & 3;
        int nt   = slot >> 8;
        int n = (nt << 4) + (lane & 15);
        int k = (kk << 5) + ((lane >> 4) << 3) + j;
        Wf[e] = f2bf(Wc[n * NCH + k]);
    } else {
        cnt4[(blockIdx.x - 64) * 256 + threadIdx.x] = make_int4(0, 0, 0, 0);
    }
}

// bucket each output row k by its source 16-pos group; entry packs (k<<4)|(p&15)
__global__ __launch_bounds__(256) void csr_fill(const int* __restrict__ idx,
                                                int* __restrict__ cnt,
                                                int* __restrict__ pairs) {
    int k = blockIdx.x * 256 + threadIdx.x;
    int p = idx[k];
    int b = p >> 4;
    int pos = atomicAdd(&cnt[b], 1);
    if (pos < CAP) pairs[b * CAP + pos] = (k << 4) | (p & 15);
}

// logits = gc^T @ W^T + b  ->  softmax  ->  scatter rows straight to out[k]
// Barrier-free: A and B to registers, LDS only for the wave-local prob transpose.
__global__ __launch_bounds__(256, 4) void gemm_scatter(const float* __restrict__ gc,
                                                       const ushort* __restrict__ Wf,
                                                       const float* __restrict__ bias,
                                                       const int* __restrict__ cnt,
                                                       const int* __restrict__ pairs,
                                                       float* __restrict__ out) {
    __shared__ ushort AO[64 * NCLS];   // 16 KiB: fp16 prob transpose, wave-local regions

    const int t    = threadIdx.x;
    const int lane = t & 63;
    const int wv   = t >> 6;
    const int l15  = lane & 15;
    const int quad = lane >> 4;
    const int m0   = blockIdx.x << 6;
    const int mw   = m0 + (wv << 4) + l15;      // this lane's A position

    // ---- scatter metadata preload (independent of everything else)
    const int bkt = (blockIdx.x << 2) + wv;
    int nb = cnt[bkt];
    int pkr = 0;
    if (lane < CAP) pkr = pairs[bkt * CAP + lane];

    // ---- A: lane loads its own 32 channels (fully coalesced 64B-line reads)
    float a_raw[32];
    #pragma unroll
    for (int kk = 0; kk < 4; ++kk)
        #pragma unroll
        for (int j = 0; j < 8; ++j)
            a_raw[(kk << 3) + j] =
                gc[(size_t)((kk << 5) + (quad << 3) + j) * HW + mw];

    // ---- B kk=0 in flight while A converts
    bf16x8 b0[8];
    #pragma unroll
    for (int nt = 0; nt < 8; ++nt)
        b0[nt] = *(const bf16x8*)&Wf[((((nt << 2) + 0) << 6) + lane) << 3];

    // ---- convert A to fragments (frees raw regs)
    bf16x8 afr[4];
    #pragma unroll
    for (int kk = 0; kk < 4; ++kk) {
        ushort2* ap = (ushort2*)&afr[kk];
        #pragma unroll
        for (int jj = 0; jj < 4; ++jj) {
            __hip_bfloat162 pk = __float22bfloat162_rn(
                make_float2(a_raw[(kk << 3) + 2 * jj], a_raw[(kk << 3) + 2 * jj + 1]));
            ap[jj] = *(ushort2*)&pk;
        }
    }

    // ---- MFMA: 16 rows x 128 cols per wave, K=128 in 4 steps; B single-step lookahead
    f32x4 acc[8];
    #pragma unroll
    for (int i = 0; i < 8; ++i) acc[i] = (f32x4){0.f, 0.f, 0.f, 0.f};

    #pragma unroll
    for (int kk = 0; kk < 4; ++kk) {
        bf16x8 bn[8];
        if (kk < 3) {
            #pragma unroll
            for (int nt = 0; nt < 8; ++nt)
                bn[nt] = *(const bf16x8*)&Wf[((((nt << 2) + kk + 1) << 6) + lane) << 3];
        }
        #pragma unroll
        for (int nt = 0; nt < 8; ++nt)
            acc[nt] = __builtin_amdgcn_mfma_f32_16x16x32_bf16(afr[kk], b0[nt], acc[nt], 0, 0, 0);
        #pragma unroll
        for (int nt = 0; nt < 8; ++nt) b0[nt] = bn[nt];
    }

    // ---- bias (loaded late to keep register peak low; L2-hot)
    float bcol[8];
    #pragma unroll
    for (int nt = 0; nt < 8; ++nt) bcol[nt] = bias[(nt << 4) + l15];

    // ---- softmax in place (C/D layout: col=l15+nt*16, row=quad*4+rr)
    float inv[4];
    #pragma unroll
    for (int rr = 0; rr < 4; ++rr) {
        float s = 0.f;
        #pragma unroll
        for (int nt = 0; nt < 8; ++nt) {
            acc[nt][rr] = __expf(acc[nt][rr] + bcol[nt]);
            s += acc[nt][rr];
        }
        s += __shfl_xor(s, 1, 64);
        s += __shfl_xor(s, 2, 64);
        s += __shfl_xor(s, 4, 64);
        s += __shfl_xor(s, 8, 64);
        inv[rr] = 1.0f / s;
    }

    // ---- transpose probs (fp16) into the wave's OWN 16-row LDS region (no barrier):
    // chunk swizzle g(quad) = ((quad&1)<<2)|(quad&2) — 2-way max on banks (free)
    const int g = ((quad & 1) << 2) | (quad & 2);
    #pragma unroll
    for (int nt = 0; nt < 8; ++nt) {
        int cl = ((nt << 1) + (l15 >> 3)) ^ g;
        #pragma unroll
        for (int rr = 0; rr < 4; ++rr) {
            int row = (wv << 4) + (quad << 2) + rr;
            AO[(row << 7) + (cl << 3) + (l15 & 7)] =
                __half_as_ushort(__float2half_rn(acc[nt][rr] * inv[rr]));
        }
    }
    // compiler inserts lgkmcnt wait before the dependent reads below (same wave)

    // ---- scatter this wave's bucket: metadata already in registers
    nb = min(nb, CAP);
    for (int i = 0; i < nb; ++i) {
        int pk  = __shfl(pkr, i, 64);
        int row = pk & 15;                      // wave-local row
        int k   = pk >> 4;
        int qd  = row >> 2;                     // writer quad for this row
        int gq  = ((qd & 1) << 2) | (qd & 2);
        int cl  = (lane >> 2) ^ gq;
        __half2 h = *(const __half2*)&AO[(((wv << 4) + row) << 7) + (cl << 3) + ((lane << 1) & 7)];
        float2 f = __half22float2(h);
        *(float2*)&out[((size_t)k << 7) + (lane << 1)] = f;
    }
}

extern "C" void kernel_launch(void* const* d_in, const int* in_sizes, int n_in,
                              void* d_out, int out_size, void* d_ws, size_t ws_size,
                              hipStream_t stream) {
    const float* gc   = (const float*)d_in[0];   // [1,128,512,512] fp32
    const int*   idx  = (const int*)d_in[1];     // [1,131072] int32
    const float* Wc   = (const float*)d_in[2];   // [128,128] fp32
    const float* bias = (const float*)d_in[3];   // [128] fp32
    float* out = (float*)d_out;                  // [131072,128] fp32

    char* ws = (char*)d_ws;
    int*    cnt   = (int*)(ws);                  // 16384 ints (64 KiB)
    int*    pairs = (int*)(ws + 0x10000);        // 16384*48 ints (3 MiB)
    ushort* Wf    = (ushort*)(ws + 0x400000);    // 16384 bf16 (32 KiB)

    prep        <<<dim3(80),        dim3(256), 0, stream>>>(Wc, Wf, (int4*)cnt);
    csr_fill    <<<dim3(KROWS/256), dim3(256), 0, stream>>>(idx, cnt, pairs);
    gemm_scatter<<<dim3(HW/64),     dim3(256), 0, stream>>>(gc, Wf, bias, cnt, pairs, out);
}